// Round 3
// baseline (251.829 us; speedup 1.0000x reference)
//
#include <hip/hip_runtime.h>

// IntegerNeuron: T-step integrate-fire scan over [T,B,C,H,W].
// T=8, B=32, C=128, H=32, W=32. Memory-bound: 128 MiB in + 128 MiB out.
//
// R1 post-mortem: serial per-t load->wait->compute->store loop was
// latency-bound (2.3 TB/s, VALUBusy 5%, VGPR=24 proves no load hoisting).
// R2/R3: prefetch all 8 float4 loads into registers (loads are address-
// independent; only the mem recurrence is serial), then run the T-scan from
// registers. Nontemporal spike stores (native ext_vector_type — the builtin
// rejects HIP_vector_type) to reduce L3 eviction of the input.
//
// Numerics: bit-exact vs fp32 reference (hard threshold spike = mem >= vth).
//   drive = x * tau; mem = (mem + drive) + bias_scaled;
//   spike = (mem >= vth_scaled); mem -= spike * vth_scaled.
// tau=4.0 is a power of two so x*tau is exact (FMA contraction harmless);
// no reassociation at -O3 without -ffast-math; jnp.round == RNE == rintf.

constexpr int T_STEPS = 8;
constexpr int NB = 32, NC = 128, NH = 32, NW = 32;
constexpr int NSP = NB * NC * NH * NW;   // 4,194,304 spatial positions
constexpr int N4  = NSP / 4;             // 1,048,576 float4 positions
constexpr int HW4 = (NH * NW) / 4;       // 256 float4 per (b,c) plane

typedef float floatx4 __attribute__((ext_vector_type(4)));  // native vec for builtins

__global__ __launch_bounds__(256) void IntegerNeuron_84842783965742_kernel(
    const float4* __restrict__ x,           // [T, B, C, H, W] as float4
    const float*  __restrict__ prev_scale,  // [C]
    const float*  __restrict__ prev_bias,   // [C]
    const float*  __restrict__ vth,         // scalar
    const int*    __restrict__ tau,         // scalar int
    const int*    __restrict__ is_first,    // scalar int
    floatx4*      __restrict__ out)         // [T, B, C, H, W] as float4
{
    const int i = blockIdx.x * blockDim.x + threadIdx.x;   // float4 index
    const int c = (i / HW4) % NC;                          // channel

    // Issue all 8 independent loads first — 8 global_load_dwordx4 in flight,
    // one HBM latency exposure instead of eight.
    float4 xv[T_STEPS];
    #pragma unroll
    for (int t = 0; t < T_STEPS; ++t) {
        xv[t] = x[(size_t)t * N4 + i];
    }

    const float tau_f = (float)tau[0];
    const float denom = prev_scale[c] + 1e-12f;
    const float bs = rintf(prev_bias[c] * tau_f / denom);  // bias_scaled[c]
    const float vs = rintf(vth[0] * tau_f / denom);        // vth_scaled[c]
    const float mul = is_first[0] ? 1.0f : tau_f;          // drive multiplier

    float m0 = 0.0f, m1 = 0.0f, m2 = 0.0f, m3 = 0.0f;      // mem in VGPRs

    #pragma unroll
    for (int t = 0; t < T_STEPS; ++t) {
        // mem = (mem + x*tau) + bias_scaled — reference association.
        m0 = (m0 + xv[t].x * mul) + bs;
        m1 = (m1 + xv[t].y * mul) + bs;
        m2 = (m2 + xv[t].z * mul) + bs;
        m3 = (m3 + xv[t].w * mul) + bs;

        floatx4 sp;
        sp.x = (m0 >= vs) ? 1.0f : 0.0f;
        sp.y = (m1 >= vs) ? 1.0f : 0.0f;
        sp.z = (m2 >= vs) ? 1.0f : 0.0f;
        sp.w = (m3 >= vs) ? 1.0f : 0.0f;

        // soft reset: spike and vs are integer-valued, product exact.
        m0 -= sp.x * vs;
        m1 -= sp.y * vs;
        m2 -= sp.z * vs;
        m3 -= sp.w * vs;

        // Streaming output, never re-read: nontemporal to spare L2/L3.
        __builtin_nontemporal_store(sp, &out[(size_t)t * N4 + i]);
    }
}

extern "C" void kernel_launch(void* const* d_in, const int* in_sizes, int n_in,
                              void* d_out, int out_size, void* d_ws, size_t ws_size,
                              hipStream_t stream) {
    const float4* x          = (const float4*)d_in[0];
    const float*  prev_scale = (const float*)d_in[1];
    const float*  prev_bias  = (const float*)d_in[2];
    const float*  vth        = (const float*)d_in[3];
    const int*    tau        = (const int*)d_in[4];
    const int*    is_first   = (const int*)d_in[5];
    floatx4*      out        = (floatx4*)d_out;

    dim3 block(256);
    dim3 grid(N4 / 256);   // 4096 blocks
    IntegerNeuron_84842783965742_kernel<<<grid, block, 0, stream>>>(
        x, prev_scale, prev_bias, vth, tau, is_first, out);
}

// Round 4
// 251.812 us; speedup vs baseline: 1.0001x; 1.0001x over previous
//
#include <hip/hip_runtime.h>

// IntegerNeuron: T-step integrate-fire scan over [T,B,C,H,W].
// T=8, B=32, C=128, H=32, W=32. Memory-bound: 128 MiB in + 128 MiB out.
//
// R3 post-mortem: VGPR_Count stayed 24 => the compiler SANK the 8 prefetch
// loads back into the per-t loop. vmcnt is a FIFO shared by loads+stores, so
// "load t; wait; compute; store t" makes every wait-for-load-t also drain
// store t-1 — 8 store-latency exposures per thread => 2.2 TB/s ceiling.
// R4: __builtin_amdgcn_sched_barrier(0) pins all 8 loads before the compute
// loop. Loads become the 8 oldest vmcnt entries; waits for them (vmcnt(7-t))
// never block on younger stores. One latency exposure per thread.
//
// Numerics: bit-exact vs fp32 reference (hard threshold spike = mem >= vth).
//   drive = x * tau; mem = (mem + drive) + bias_scaled;
//   spike = (mem >= vth_scaled); mem -= spike * vth_scaled.
// tau=4.0 is a power of two so x*tau is exact (FMA contraction harmless);
// no reassociation at -O3 without -ffast-math; jnp.round == RNE == rintf.

constexpr int T_STEPS = 8;
constexpr int NB = 32, NC = 128, NH = 32, NW = 32;
constexpr int NSP = NB * NC * NH * NW;   // 4,194,304 spatial positions
constexpr int N4  = NSP / 4;             // 1,048,576 float4 positions
constexpr int HW4 = (NH * NW) / 4;       // 256 float4 per (b,c) plane

typedef float floatx4 __attribute__((ext_vector_type(4)));  // native vec for builtins

__global__ __launch_bounds__(256) void IntegerNeuron_84842783965742_kernel(
    const floatx4* __restrict__ x,          // [T, B, C, H, W] as float4
    const float*   __restrict__ prev_scale, // [C]
    const float*   __restrict__ prev_bias,  // [C]
    const float*   __restrict__ vth,        // scalar
    const int*     __restrict__ tau,        // scalar int
    const int*     __restrict__ is_first,   // scalar int
    floatx4*       __restrict__ out)        // [T, B, C, H, W] as float4
{
    const int i = blockIdx.x * blockDim.x + threadIdx.x;   // float4 index
    const int c = (i / HW4) % NC;                          // channel

    // Issue all 8 independent loads first — 8 global_load_dwordx4 in flight.
    floatx4 xv[T_STEPS];
    #pragma unroll
    for (int t = 0; t < T_STEPS; ++t) {
        xv[t] = x[(size_t)t * N4 + i];
    }
    // Hard scheduling fence: nothing moves across. Keeps the 8 loads issued
    // before any compute/store, so they're the oldest vmcnt FIFO entries.
    __builtin_amdgcn_sched_barrier(0);

    const float tau_f = (float)tau[0];
    const float denom = prev_scale[c] + 1e-12f;
    const float bs = rintf(prev_bias[c] * tau_f / denom);  // bias_scaled[c]
    const float vs = rintf(vth[0] * tau_f / denom);        // vth_scaled[c]
    const float mul = is_first[0] ? 1.0f : tau_f;          // drive multiplier

    float m0 = 0.0f, m1 = 0.0f, m2 = 0.0f, m3 = 0.0f;      // mem in VGPRs

    #pragma unroll
    for (int t = 0; t < T_STEPS; ++t) {
        // mem = (mem + x*tau) + bias_scaled — reference association.
        m0 = (m0 + xv[t].x * mul) + bs;
        m1 = (m1 + xv[t].y * mul) + bs;
        m2 = (m2 + xv[t].z * mul) + bs;
        m3 = (m3 + xv[t].w * mul) + bs;

        floatx4 sp;
        sp.x = (m0 >= vs) ? 1.0f : 0.0f;
        sp.y = (m1 >= vs) ? 1.0f : 0.0f;
        sp.z = (m2 >= vs) ? 1.0f : 0.0f;
        sp.w = (m3 >= vs) ? 1.0f : 0.0f;

        // soft reset: spike and vs are integer-valued, product exact.
        m0 -= sp.x * vs;
        m1 -= sp.y * vs;
        m2 -= sp.z * vs;
        m3 -= sp.w * vs;

        // Streaming output, never re-read: nontemporal to spare L2/L3.
        __builtin_nontemporal_store(sp, &out[(size_t)t * N4 + i]);
    }
}

extern "C" void kernel_launch(void* const* d_in, const int* in_sizes, int n_in,
                              void* d_out, int out_size, void* d_ws, size_t ws_size,
                              hipStream_t stream) {
    const floatx4* x          = (const floatx4*)d_in[0];
    const float*   prev_scale = (const float*)d_in[1];
    const float*   prev_bias  = (const float*)d_in[2];
    const float*   vth        = (const float*)d_in[3];
    const int*     tau        = (const int*)d_in[4];
    const int*     is_first   = (const int*)d_in[5];
    floatx4*       out        = (floatx4*)d_out;

    dim3 block(256);
    dim3 grid(N4 / 256);   // 4096 blocks
    IntegerNeuron_84842783965742_kernel<<<grid, block, 0, stream>>>(
        x, prev_scale, prev_bias, vth, tau, is_first, out);
}

// Round 5
// 248.379 us; speedup vs baseline: 1.0139x; 1.0138x over previous
//
#include <hip/hip_runtime.h>

// IntegerNeuron: T-step integrate-fire scan over [T,B,C,H,W].
// T=8, B=32, C=128, H=32, W=32. 128 MiB in + 128 MiB out.
//
// R4 post-mortem: VGPR=28 — even sched_barrier(0) couldn't keep loads
// hoisted (it's IntrNoMem: the SelectionDAG scheduler sinks loads to uses
// before the MIR fence applies). New evidence: dispatches whose reads were
// 100% L3-served (FETCH=0) ran at the SAME 92 us => read path irrelevant.
// Bottleneck is the WRITE chain: vmcnt is a FIFO over loads AND stores, so
// the per-iteration wait-for-load also drains the previous store => <=1
// outstanding store/wave => writes cap at 1.4 TB/s.
//
// R5: buffer all 8 spike float4s in registers, store in a burst AFTER the
// scan. asm volatile memory fence (zero instructions, full compiler-level
// ordering at IR+DAG+MIR) keeps stores below / loads above. In-loop waits
// now cover loads only; stores from all waves pile up concurrently and the
// write stream runs at the write-BW ceiling instead of the ack-latency chain.
//
// Numerics: bit-exact vs fp32 reference (hard threshold spike = mem >= vth).
//   drive = x*tau; mem = (mem + drive) + bias_scaled;
//   spike = (mem >= vth_scaled); mem -= spike*vth_scaled.
// tau=4.0 (power of two) => x*tau exact => FMA contraction harmless; no
// reassociation at -O3 without -ffast-math; jnp.round == RNE == rintf.

constexpr int T_STEPS = 8;
constexpr int NB = 32, NC = 128, NH = 32, NW = 32;
constexpr int NSP = NB * NC * NH * NW;   // 4,194,304 spatial positions
constexpr int N4  = NSP / 4;             // 1,048,576 float4 positions
constexpr int HW4 = (NH * NW) / 4;       // 256 float4 per (b,c) plane

typedef float floatx4 __attribute__((ext_vector_type(4)));

__global__ __launch_bounds__(256) void IntegerNeuron_84842783965742_kernel(
    const floatx4* __restrict__ x,          // [T, B, C, H, W] as float4
    const float*   __restrict__ prev_scale, // [C]
    const float*   __restrict__ prev_bias,  // [C]
    const float*   __restrict__ vth,        // scalar
    const int*     __restrict__ tau,        // scalar int
    const int*     __restrict__ is_first,   // scalar int
    floatx4*       __restrict__ out)        // [T, B, C, H, W] as float4
{
    const int i = blockIdx.x * blockDim.x + threadIdx.x;   // float4 index
    const int c = (i / HW4) % NC;                          // channel

    const float tau_f = (float)tau[0];
    const float denom = prev_scale[c] + 1e-12f;
    const float bs = rintf(prev_bias[c] * tau_f / denom);  // bias_scaled[c]
    const float vs = rintf(vth[0] * tau_f / denom);        // vth_scaled[c]
    const float mul = is_first[0] ? 1.0f : tau_f;          // drive multiplier

    float m0 = 0.0f, m1 = 0.0f, m2 = 0.0f, m3 = 0.0f;      // mem in VGPRs

    floatx4 sp_buf[T_STEPS];                               // spikes, registers

    #pragma unroll
    for (int t = 0; t < T_STEPS; ++t) {
        const floatx4 xv = x[(size_t)t * N4 + i];

        // mem = (mem + x*tau) + bias_scaled — reference association.
        m0 = (m0 + xv.x * mul) + bs;
        m1 = (m1 + xv.y * mul) + bs;
        m2 = (m2 + xv.z * mul) + bs;
        m3 = (m3 + xv.w * mul) + bs;

        floatx4 sp;
        sp.x = (m0 >= vs) ? 1.0f : 0.0f;
        sp.y = (m1 >= vs) ? 1.0f : 0.0f;
        sp.z = (m2 >= vs) ? 1.0f : 0.0f;
        sp.w = (m3 >= vs) ? 1.0f : 0.0f;

        // soft reset: spike and vs are integer-valued, product exact.
        m0 -= sp.x * vs;
        m1 -= sp.y * vs;
        m2 -= sp.z * vs;
        m3 -= sp.w * vs;

        sp_buf[t] = sp;
    }

    // Full compiler memory fence (no instruction emitted): the out-stores
    // cannot be hoisted above this, the x-loads cannot be sunk below it.
    // Keeps every in-loop s_waitcnt free of store-drain coupling.
    asm volatile("" ::: "memory");

    #pragma unroll
    for (int t = 0; t < T_STEPS; ++t) {
        out[(size_t)t * N4 + i] = sp_buf[t];
    }
}

extern "C" void kernel_launch(void* const* d_in, const int* in_sizes, int n_in,
                              void* d_out, int out_size, void* d_ws, size_t ws_size,
                              hipStream_t stream) {
    const floatx4* x          = (const floatx4*)d_in[0];
    const float*   prev_scale = (const float*)d_in[1];
    const float*   prev_bias  = (const float*)d_in[2];
    const float*   vth        = (const float*)d_in[3];
    const int*     tau        = (const int*)d_in[4];
    const int*     is_first   = (const int*)d_in[5];
    floatx4*       out        = (floatx4*)d_out;

    dim3 block(256);
    dim3 grid(N4 / 256);   // 4096 blocks
    IntegerNeuron_84842783965742_kernel<<<grid, block, 0, stream>>>(
        x, prev_scale, prev_bias, vth, tau, is_first, out);
}